// Round 11
// baseline (1311.740 us; speedup 1.0000x reference)
//
#include <hip/hip_runtime.h>

// LSTM B=512,T=512,D=128,H=64,O=1. Gate order i,f,g,o.
// K1: pre[b][t][g] = x[b,t,:]@Wih0^T + bih0+bhh0  (fp32 register-tiled GEMM).
// K2: fused 2-layer recurrence. 512 blocks (1 batch) x 768 thr (12 waves, 3/EU).
//   REGALLOC WAR (R3..R10): loop-invariant weight LOADS get sunk into the loop
//   by pre-RA pressure heuristics regardless of launch bounds (R8 VGPR=72),
//   asm pins (R9 identical), or waves_per_eu(3,3) honest budget (R10 VGPR=68,
//   occupancy clamp applied but loads still sunk). Fix here: make sinking
//   ILLEGAL, not unprofitable — w = fmaf(pz, w, w) where pz=h0s[0][63] is an
//   LDS value (cross-thread zero, unprovable, unfoldable without fast-math)
//   whose slot is overwritten during the loop => the fmaf cannot be re-executed
//   later => weights must stay live in registers (or visibly spill: WRITE_SIZE).
//   Numerically exact: 0*w + w = w.
//   Geometry (proven absmax=0.0 in R10): sub-block m=tid/256 owns matrix m
//   (0:Whh0,1:Wih1,2:Whh1); thread (j=s>>2, qt=s&3) holds rows {g*64+j},
//   k-slice [16qt,16qt+16). Layer skew -> all three matvecs consume OLD state,
//   fully parallel. Quad butterfly (DPP xor1+xor2) -> lane has all 4 gate sums
//   of unit j. Sub-2 publishes via zp2; in-register cell updates. 2 barriers/step.
// ws: 512*512*256*4 = 256 MiB fp32 pre buffer (read-only in K2).

#define TSTEPS 512

__device__ __forceinline__ float sigf(float x){ return 1.0f/(1.0f+__expf(-x)); }
__device__ __forceinline__ float tanh_fast(float x){
  float ax=fabsf(x); float e=__expf(-2.0f*ax); float r=(1.0f-e)/(1.0f+e); return copysignf(r,x);
}
// a + dpp_shuffle(b); CTRL: 0xB1=quad_perm xor1, 0x4E=quad_perm xor2
template<int CTRL>
__device__ __forceinline__ float add_dpp(float a, float b){
  return a + __int_as_float(__builtin_amdgcn_update_dpp(
      0, __float_as_int(b), CTRL, 0xF, 0xF, true));
}

// ---------------- K1: input projection GEMM (fp32 VALU) ----------------
__global__ __launch_bounds__(256) void k_inproj(
    const float* __restrict__ x, const float* __restrict__ W,
    const float* __restrict__ bih, const float* __restrict__ bhh,
    float* __restrict__ pre)
{
    __shared__ float xs[64][128];
    const int tid = threadIdx.x;
    const long row0 = (long)blockIdx.x * 64;

    const float4* __restrict__ xv = (const float4*)(x + row0 * 128);
    float4* xsv = (float4*)(&xs[0][0]);
#pragma unroll
    for (int i = 0; i < 8; ++i) xsv[tid + 256 * i] = xv[tid + 256 * i];
    __syncthreads();

    const int tx = tid & 63;
    const int ty = tid >> 6;

    float acc[16][4];
#pragma unroll
    for (int i = 0; i < 16; ++i)
#pragma unroll
        for (int j = 0; j < 4; ++j) acc[i][j] = 0.0f;

#pragma unroll 1
    for (int kc = 0; kc < 16; ++kc) {
        const int k0 = kc * 8;
        float4 w0[4], w1[4];
#pragma unroll
        for (int j = 0; j < 4; ++j) {
            const float* wr = W + (tx + 64 * j) * 128 + k0;
            w0[j] = *(const float4*)wr;
            w1[j] = *(const float4*)(wr + 4);
        }
#pragma unroll
        for (int i = 0; i < 16; ++i) {
            const int r = ty * 16 + i;
            float4 a0 = *(const float4*)(&xs[r][k0]);
            float4 a1 = *(const float4*)(&xs[r][k0 + 4]);
#pragma unroll
            for (int j = 0; j < 4; ++j) {
                float s = acc[i][j];
                s = fmaf(a0.x, w0[j].x, s); s = fmaf(a0.y, w0[j].y, s);
                s = fmaf(a0.z, w0[j].z, s); s = fmaf(a0.w, w0[j].w, s);
                s = fmaf(a1.x, w1[j].x, s); s = fmaf(a1.y, w1[j].y, s);
                s = fmaf(a1.z, w1[j].z, s); s = fmaf(a1.w, w1[j].w, s);
                acc[i][j] = s;
            }
        }
    }

    float bsum[4];
#pragma unroll
    for (int j = 0; j < 4; ++j) { const int g = tx + 64 * j; bsum[j] = bih[g] + bhh[g]; }
#pragma unroll
    for (int i = 0; i < 16; ++i) {
        const long r = row0 + ty * 16 + i;
        float* pr = pre + r * 256;
#pragma unroll
        for (int j = 0; j < 4; ++j) pr[tx + 64 * j] = acc[i][j] + bsum[j];
    }
}

// ---------------- K2: fused 2-layer recurrence + head ----------------
__global__
__attribute__((amdgpu_flat_work_group_size(768, 768)))
__attribute__((amdgpu_waves_per_eu(3, 3)))
void k_fused(
    const float* __restrict__ Whh0, const float* __restrict__ Wih1,
    const float* __restrict__ Whh1,
    const float* __restrict__ bih1, const float* __restrict__ bhh1,
    const float* __restrict__ Wfc,  const float* __restrict__ bfc,
    const float* __restrict__ pre,  float* __restrict__ out)
{
    const int tid = threadIdx.x;
    const int m   = tid >> 8;        // sub-block: 0=Whh0, 1=Wih1, 2=Whh1
    const int s   = tid & 255;
    const int j   = s >> 2;          // hidden unit 0..63
    const int qt  = s & 3;           // k-quarter (16 of 64)
    const int b   = blockIdx.x;

    __shared__ __align__(16) float h0s[2][64];
    __shared__ __align__(16) float h1s[2][64];
    __shared__ float zp2[4][64];

    // ---- 64 weight floats/thread: rows g*64+j of matrix m, k in [16qt,16qt+16)
    const float* Wm = (m == 0) ? Whh0 : (m == 1) ? Wih1 : Whh1;
    float w[4][16];
#pragma unroll
    for (int g = 0; g < 4; ++g) {
        const float4* src = (const float4*)(Wm + (g * 64 + j) * 64 + qt * 16);
#pragma unroll
        for (int i = 0; i < 4; ++i) {
            float4 v = src[i];
            w[g][4*i+0] = v.x; w[g][4*i+1] = v.y; w[g][4*i+2] = v.z; w[g][4*i+3] = v.w;
        }
    }
    float bias1v[4];
#pragma unroll
    for (int g = 0; g < 4; ++g) bias1v[g] = bih1[g * 64 + j] + bhh1[g * 64 + j];

    if (tid < 64) { h0s[0][tid] = 0.0f; h1s[0][tid] = 0.0f; }
    __syncthreads();

    // ---- anti-sink transform: pz is 0.0f HERE (and only here — h0s[0] is
    // overwritten from n=1 on). w := 0*w + w, bit-exact, but now each weight is
    // the result of an FMA whose operand cannot be re-derived inside the loop
    // => loads can no longer be sunk; values must stay in VGPRs (or visibly
    // spill to scratch, which WRITE_SIZE would expose).
    {
        const float pz = h0s[0][63];
#pragma unroll
        for (int g = 0; g < 4; ++g) {
#pragma unroll
            for (int k = 0; k < 16; ++k) w[g][k] = fmaf(pz, w[g][k], w[g][k]);
            bias1v[g] = fmaf(pz, bias1v[g], bias1v[g]);
        }
    }

    const float* __restrict__ pb = pre + (size_t)b * TSTEPS * 256;
    float pc[4];
#pragma unroll
    for (int g = 0; g < 4; ++g) pc[g] = pb[g * 64 + j];   // t=0 (used by m==0)

    float cst = 0.0f;   // c-state: (m==0,qt==0) -> c0[j]; (m==1,qt==0) -> c1[j]
    int p = 0;

#pragma unroll 1
    for (int n = 0; n <= TSTEPS; ++n) {
        // h slice for my matrix (old state, parity p): m<2 -> h0, m==2 -> h1
        const float* hsrc = (m == 2) ? &h1s[p][qt * 16] : &h0s[p][qt * 16];
        float hv[16];
#pragma unroll
        for (int i = 0; i < 4; ++i) {
            float4 v = *(const float4*)(hsrc + 4 * i);
            hv[4*i+0] = v.x; hv[4*i+1] = v.y; hv[4*i+2] = v.z; hv[4*i+3] = v.w;
        }

        // prefetch next pre0 (sub-0 only)
        float pn_[4] = {0, 0, 0, 0};
        const int tn = (n < TSTEPS - 1) ? n + 1 : 0;
        if (m == 0) {
#pragma unroll
            for (int g = 0; g < 4; ++g) pn_[g] = pb[tn * 256 + g * 64 + j];
        }

        // ---- dots: 4 gates x 16 k, 4 independent sub-chains each ----
        float z[4];
#pragma unroll
        for (int g = 0; g < 4; ++g) {
            float t0 = 0, t1 = 0, t2 = 0, t3 = 0;
#pragma unroll
            for (int k = 0; k < 4; ++k) {
                t0 = fmaf(w[g][k],      hv[k],      t0);
                t1 = fmaf(w[g][4 + k],  hv[4 + k],  t1);
                t2 = fmaf(w[g][8 + k],  hv[8 + k],  t2);
                t3 = fmaf(w[g][12 + k], hv[12 + k], t3);
            }
            float sum = (t0 + t1) + (t2 + t3);
            sum = add_dpp<0xB1>(sum, sum);   // quad xor1
            sum = add_dpp<0x4E>(sum, sum);   // quad xor2 -> full 64-k sum
            z[g] = sum;
        }

        // sub-2 publishes Whh1.h1 partials
        if (m == 2 && qt == 0) {
#pragma unroll
            for (int g = 0; g < 4; ++g) zp2[g][j] = z[g];
        }
        __syncthreads();   // zp2 visible

        // ---- cell updates (qt==0 lanes) ----
        if (qt == 0) {
            if (m == 0) {
                if (n < TSTEPS) {
                    float z0 = z[0] + pc[0], z1 = z[1] + pc[1];
                    float z2 = z[2] + pc[2], z3 = z[3] + pc[3];
                    float i_ = sigf(z0), f_ = sigf(z1), g_ = tanh_fast(z2), o_ = sigf(z3);
                    cst = fmaf(f_, cst, i_ * g_);
                    h0s[p ^ 1][j] = o_ * tanh_fast(cst);
                }
            } else if (m == 1) {
                if (n >= 1) {
                    float z0 = z[0] + bias1v[0] + zp2[0][j];
                    float z1 = z[1] + bias1v[1] + zp2[1][j];
                    float z2 = z[2] + bias1v[2] + zp2[2][j];
                    float z3 = z[3] + bias1v[3] + zp2[3][j];
                    float i_ = sigf(z0), f_ = sigf(z1), g_ = tanh_fast(z2), o_ = sigf(z3);
                    cst = fmaf(f_, cst, i_ * g_);
                    h1s[p ^ 1][j] = o_ * tanh_fast(cst);
                }
            }
        }
        __syncthreads();   // new h visible
        p ^= 1;
        if (m == 0) {
#pragma unroll
            for (int g = 0; g < 4; ++g) pc[g] = pn_[g];
        }
    }

    // ---- head: out[b] = h1_{T-1} . Wfc + bfc (wave 0) ----
    if (tid < 64) {
        float v = h1s[p][tid] * Wfc[tid];
#pragma unroll
        for (int off = 32; off > 0; off >>= 1) v += __shfl_down(v, off);
        if (tid == 0) out[b] = v + bfc[0];
    }
}

extern "C" void kernel_launch(void* const* d_in, const int* in_sizes, int n_in,
                              void* d_out, int out_size, void* d_ws, size_t ws_size,
                              hipStream_t stream)
{
    const float* x    = (const float*)d_in[0];
    const float* Wih0 = (const float*)d_in[1];
    const float* Whh0 = (const float*)d_in[2];
    const float* bih0 = (const float*)d_in[3];
    const float* bhh0 = (const float*)d_in[4];
    const float* Wih1 = (const float*)d_in[5];
    const float* Whh1 = (const float*)d_in[6];
    const float* bih1 = (const float*)d_in[7];
    const float* bhh1 = (const float*)d_in[8];
    const float* Wfc  = (const float*)d_in[9];
    const float* bfc  = (const float*)d_in[10];
    float* out = (float*)d_out;
    float* pre = (float*)d_ws;  // [B][T][256] fp32 = 256 MiB

    k_inproj<<<4096, 256, 0, stream>>>(x, Wih0, bih0, bhh0, pre);
    k_fused<<<512, 768, 0, stream>>>(Whh0, Wih1, Whh1, bih1, bhh1, Wfc, bfc, pre, out);
}

// Round 12
// 1012.220 us; speedup vs baseline: 1.2959x; 1.2959x over previous
//
#include <hip/hip_runtime.h>

// LSTM B=512,T=512,D=128,H=64,O=1. Gate order i,f,g,o.
// K1: pre = x@Wih0^T + bih0+bhh0 (fp32 register-tiled GEMM, exact).
// K2: fused 2-layer recurrence, weights LDS-STATIONARY in fp16.
//   R3..R11 post-mortems: the backend refuses to keep >~32 loop-invariant
//   floats/thread in VGPRs (sinks loads / re-executes whole chains) under
//   every knob: launch_bounds, waves_per_eu(3,3), asm pins, fmaf-on-LDS-zero.
//   Weights have AI=1 FMA/weight/step -> need ~64KB/step/CU BW -> LDS tier
//   (128-256 B/clk), not L2 (~60 B/clk = what the sunk loads were paying).
//   All 3 matrices fp32 = 192KB > 160KB LDS -> fp16 (96KB). Error budget:
//   w rel 2.4e-4 (RNE) + h-as-fp16 similar -> absmax ~3e-4..1e-3 << 3.7e-3.
//   Geometry: 256 blocks x 768 thr, 2 batches/block -> all 256 CUs, 1 pass.
//   Thread = gate-row r=tid of matrix m=r>>8 (0:Whh0,1:Wih1,2:Whh1), full k=64
//   as 32 x v_dot2_f32_f16 per batch. wlds[kp][r]: bank=r%32, conflict-free.
//   h broadcast (same addr/wave). z exchange via LDS; skewed layers (R10's
//   proven dataflow); 2 barriers/step. Updaters tid<256 = (c,layer,unit).
// ws: 512*512*256*4 = 256 MiB fp32 pre (read-only in K2).

#define TSTEPS 512

typedef _Float16 h2v __attribute__((ext_vector_type(2)));
union HU { unsigned u; h2v h; };

__device__ __forceinline__ float sigf(float x){ return 1.0f/(1.0f+__expf(-x)); }
__device__ __forceinline__ float tanh_fast(float x){
  float ax=fabsf(x); float e=__expf(-2.0f*ax); float r=(1.0f-e)/(1.0f+e); return copysignf(r,x);
}
__device__ __forceinline__ unsigned packh(float a, float b){
  unsigned short la = __builtin_bit_cast(unsigned short, (_Float16)a);
  unsigned short lb = __builtin_bit_cast(unsigned short, (_Float16)b);
  return (unsigned)la | ((unsigned)lb << 16);
}
__device__ __forceinline__ float dot2f(unsigned wu, unsigned hu, float acc){
#if __has_builtin(__builtin_amdgcn_fdot2)
  HU w; w.u = wu; HU x; x.u = hu;
  return __builtin_amdgcn_fdot2(w.h, x.h, acc, false);
#else
  HU w; w.u = wu; HU x; x.u = hu;
  acc = fmaf((float)w.h[0], (float)x.h[0], acc);
  acc = fmaf((float)w.h[1], (float)x.h[1], acc);
  return acc;
#endif
}

// ---------------- K1: input projection GEMM (fp32 VALU) ----------------
__global__ __launch_bounds__(256) void k_inproj(
    const float* __restrict__ x, const float* __restrict__ W,
    const float* __restrict__ bih, const float* __restrict__ bhh,
    float* __restrict__ pre)
{
    __shared__ float xs[64][128];
    const int tid = threadIdx.x;
    const long row0 = (long)blockIdx.x * 64;

    const float4* __restrict__ xv = (const float4*)(x + row0 * 128);
    float4* xsv = (float4*)(&xs[0][0]);
#pragma unroll
    for (int i = 0; i < 8; ++i) xsv[tid + 256 * i] = xv[tid + 256 * i];
    __syncthreads();

    const int tx = tid & 63;
    const int ty = tid >> 6;

    float acc[16][4];
#pragma unroll
    for (int i = 0; i < 16; ++i)
#pragma unroll
        for (int j = 0; j < 4; ++j) acc[i][j] = 0.0f;

#pragma unroll 1
    for (int kc = 0; kc < 16; ++kc) {
        const int k0 = kc * 8;
        float4 w0[4], w1[4];
#pragma unroll
        for (int j = 0; j < 4; ++j) {
            const float* wr = W + (tx + 64 * j) * 128 + k0;
            w0[j] = *(const float4*)wr;
            w1[j] = *(const float4*)(wr + 4);
        }
#pragma unroll
        for (int i = 0; i < 16; ++i) {
            const int r = ty * 16 + i;
            float4 a0 = *(const float4*)(&xs[r][k0]);
            float4 a1 = *(const float4*)(&xs[r][k0 + 4]);
#pragma unroll
            for (int j = 0; j < 4; ++j) {
                float s = acc[i][j];
                s = fmaf(a0.x, w0[j].x, s); s = fmaf(a0.y, w0[j].y, s);
                s = fmaf(a0.z, w0[j].z, s); s = fmaf(a0.w, w0[j].w, s);
                s = fmaf(a1.x, w1[j].x, s); s = fmaf(a1.y, w1[j].y, s);
                s = fmaf(a1.z, w1[j].z, s); s = fmaf(a1.w, w1[j].w, s);
                acc[i][j] = s;
            }
        }
    }

    float bsum[4];
#pragma unroll
    for (int j = 0; j < 4; ++j) { const int g = tx + 64 * j; bsum[j] = bih[g] + bhh[g]; }
#pragma unroll
    for (int i = 0; i < 16; ++i) {
        const long r = row0 + ty * 16 + i;
        float* pr = pre + r * 256;
#pragma unroll
        for (int j = 0; j < 4; ++j) pr[tx + 64 * j] = acc[i][j] + bsum[j];
    }
}

// ---------------- K2: fused 2-layer recurrence + head ----------------
__global__ __attribute__((amdgpu_flat_work_group_size(768, 768)))
void k_fused(
    const float* __restrict__ Whh0, const float* __restrict__ Wih1,
    const float* __restrict__ Whh1,
    const float* __restrict__ bih1, const float* __restrict__ bhh1,
    const float* __restrict__ Wfc,  const float* __restrict__ bfc,
    const float* __restrict__ pre,  float* __restrict__ out)
{
    const int tid = threadIdx.x;
    const int m  = tid >> 8;         // matrix: 0=Whh0, 1=Wih1, 2=Whh1
    const int rr = tid & 255;        // row within matrix (gate g=rr>>6, unit rr&63)

    __shared__ unsigned wlds[32][768];      // 96KB: wlds[kp][r] = fp16x2 W[r][2kp..2kp+1]
    __shared__ unsigned hp[2][2][2][32];    // 1KB: [parity][c][layer][kp] fp16x2 h
    __shared__ float zl[2][768];            // 6KB: [c][r] dot results

    // ---- build fp16 weights in LDS (one-time) ----
    {
        const float* Wm = (m == 0) ? Whh0 : ((m == 1) ? Wih1 : Whh1);
        const float2* w2 = (const float2*)(Wm + rr * 64);
#pragma unroll
        for (int kp = 0; kp < 32; ++kp) {
            float2 v = w2[kp];
            wlds[kp][tid] = packh(v.x, v.y);
        }
    }
    if (tid < 256) ((unsigned*)hp)[tid] = 0;   // h_{-1} = 0, both parities

    // ---- updater role (tid < 256): c=batch, l=layer, j=unit ----
    const int c_u = tid >> 7;
    const int l_u = (tid >> 6) & 1;
    const int j_u = tid & 63;
    const long bb = (long)blockIdx.x * 2;
    float bias1v[4] = {0, 0, 0, 0};
    float pc[4] = {0, 0, 0, 0};
    if (tid < 256) {
        if (l_u == 1) {
#pragma unroll
            for (int g = 0; g < 4; ++g) bias1v[g] = bih1[g * 64 + j_u] + bhh1[g * 64 + j_u];
        } else {
            const float* pb = pre + (bb + c_u) * TSTEPS * 256;
#pragma unroll
            for (int g = 0; g < 4; ++g) pc[g] = pb[g * 64 + j_u];   // t=0
        }
    }
    float cst = 0.0f, h1last = 0.0f;
    int p = 0;
    const int lay = (m == 2) ? 1 : 0;   // which h my matrix consumes
    __syncthreads();

#pragma unroll 1
    for (int n = 0; n <= TSTEPS; ++n) {
        // prefetch pre for t=n+1 (layer-0 updaters), issued before dot work
        float pn[4] = {0, 0, 0, 0};
        if (tid < 256 && l_u == 0) {
            const int tn = (n + 1 < TSTEPS) ? n + 1 : 0;
            const float* pb = pre + ((bb + c_u) * TSTEPS + tn) * 256;
#pragma unroll
            for (int g = 0; g < 4; ++g) pn[g] = pb[g * 64 + j_u];
        }

        // ---- dots: z[c][r] = W[r][:] . h[c][:]  (fp16 x fp16 -> fp32) ----
        float a0 = 0.0f, a1 = 0.0f;
        {
            const uint4* h0p = (const uint4*)&hp[p][0][lay][0];
            const uint4* h1p = (const uint4*)&hp[p][1][lay][0];
#pragma unroll
            for (int q = 0; q < 8; ++q) {
                uint4 ha = h0p[q], hb = h1p[q];
                unsigned ua[4] = {ha.x, ha.y, ha.z, ha.w};
                unsigned ub[4] = {hb.x, hb.y, hb.z, hb.w};
#pragma unroll
                for (int e = 0; e < 4; ++e) {
                    const unsigned wu = wlds[4 * q + e][tid];
                    a0 = dot2f(wu, ua[e], a0);
                    a1 = dot2f(wu, ub[e], a1);
                }
            }
        }
        zl[0][tid] = a0;
        zl[1][tid] = a1;
        __syncthreads();   // z ready

        // ---- cell updates ----
        if (tid < 256) {
            const bool valid = (l_u == 0) ? (n < TSTEPS) : (n >= 1);
            if (valid) {
                float z[4];
                if (l_u == 0) {
#pragma unroll
                    for (int g = 0; g < 4; ++g) z[g] = pc[g] + zl[c_u][g * 64 + j_u];
                } else {
#pragma unroll
                    for (int g = 0; g < 4; ++g)
                        z[g] = bias1v[g] + zl[c_u][256 + g * 64 + j_u] + zl[c_u][512 + g * 64 + j_u];
                }
                float i_ = sigf(z[0]), f_ = sigf(z[1]), g_ = tanh_fast(z[2]), o_ = sigf(z[3]);
                cst = fmaf(f_, cst, i_ * g_);
                float h = o_ * tanh_fast(cst);
                if (l_u) h1last = h;
                ((unsigned short*)&hp[p ^ 1][c_u][l_u][0])[j_u] =
                    __builtin_bit_cast(unsigned short, (_Float16)h);
            }
        }
        __syncthreads();   // new h visible
        p ^= 1;
        if (tid < 256 && l_u == 0) {
            pc[0] = pn[0]; pc[1] = pn[1]; pc[2] = pn[2]; pc[3] = pn[3];
        }
    }

    // ---- head: out[bb+c] = h1_{T-1} . Wfc + bfc ----
    if (tid < 256 && l_u == 1) {
        float v = h1last * Wfc[j_u];
#pragma unroll
        for (int off = 32; off > 0; off >>= 1) v += __shfl_down(v, off);
        if (j_u == 0) out[bb + c_u] = v + bfc[0];
    }
}

extern "C" void kernel_launch(void* const* d_in, const int* in_sizes, int n_in,
                              void* d_out, int out_size, void* d_ws, size_t ws_size,
                              hipStream_t stream)
{
    const float* x    = (const float*)d_in[0];
    const float* Wih0 = (const float*)d_in[1];
    const float* Whh0 = (const float*)d_in[2];
    const float* bih0 = (const float*)d_in[3];
    const float* bhh0 = (const float*)d_in[4];
    const float* Wih1 = (const float*)d_in[5];
    const float* Whh1 = (const float*)d_in[6];
    const float* bih1 = (const float*)d_in[7];
    const float* bhh1 = (const float*)d_in[8];
    const float* Wfc  = (const float*)d_in[9];
    const float* bfc  = (const float*)d_in[10];
    float* out = (float*)d_out;
    float* pre = (float*)d_ws;  // [B][T][256] fp32 = 256 MiB

    k_inproj<<<4096, 256, 0, stream>>>(x, Wih0, bih0, bhh0, pre);
    k_fused<<<256, 768, 0, stream>>>(Whh0, Wih1, Whh1, bih1, bhh1, Wfc, bfc, pre, out);
}

// Round 13
// 842.742 us; speedup vs baseline: 1.5565x; 1.2011x over previous
//
#include <hip/hip_runtime.h>

// LSTM B=512,T=512,D=128,H=64,O=1. Gate order i,f,g,o.
// K1: pre = x@Wih0^T + bih0+bhh0 (fp32 register-tiled GEMM, exact).
// K2: fused 2-layer recurrence, LDS-stationary fp16 weights (R12, 745us) with
//   the DS-issue bottleneck fixed (R12 counters: VALUBusy 40%, DS pipe serializing
//   ~440 issue-cyc/wave/step). Per-thread DS bytes = 2K(R+C), RCK=128 fixed:
//   old (R1,C2,K64)=384B; new (R4,C2,K16)=192B, all b128: 8 w-reads + 4 h-reads.
//   Quad k-split: lane ll=tid&3 owns k-slice [16ll,16ll+16) of 4 rows (quad q).
//   Select-free merge (R8/R10-proven): rows loaded permuted per lane
//   (slot0:4q+(ll&1), slot1:+2, slot2:4q+1-(ll&1), slot3:+2) so quad_perm xor1
//   merges rows; batch slots A=(ll>>1)&1 via per-lane h address so xor2 merges
//   batches. Lane ends with rows {4q+(ll&1), +2} of batch A.
//   Weights packed ONCE into per-thread streams wl4[i][tid] (lane-major) ->
//   reads AND init writes conflict-free by construction.
// ws: 512*512*256*4 = 256 MiB fp32 pre (read-only in K2).

#define TSTEPS 512

typedef _Float16 h2v __attribute__((ext_vector_type(2)));
union HU { unsigned u; h2v h; };

__device__ __forceinline__ float sigf(float x){ return 1.0f/(1.0f+__expf(-x)); }
__device__ __forceinline__ float tanh_fast(float x){
  float ax=fabsf(x); float e=__expf(-2.0f*ax); float r=(1.0f-e)/(1.0f+e); return copysignf(r,x);
}
__device__ __forceinline__ unsigned packh(float a, float b){
  unsigned short la = __builtin_bit_cast(unsigned short, (_Float16)a);
  unsigned short lb = __builtin_bit_cast(unsigned short, (_Float16)b);
  return (unsigned)la | ((unsigned)lb << 16);
}
__device__ __forceinline__ float dot2f(unsigned wu, unsigned hu, float acc){
#if __has_builtin(__builtin_amdgcn_fdot2)
  HU w; w.u = wu; HU x; x.u = hu;
  return __builtin_amdgcn_fdot2(w.h, x.h, acc, false);
#else
  HU w; w.u = wu; HU x; x.u = hu;
  acc = fmaf((float)w.h[0], (float)x.h[0], acc);
  acc = fmaf((float)w.h[1], (float)x.h[1], acc);
  return acc;
#endif
}
// a + dpp_quad_perm(b); 0xB1 = xor1 [1,0,3,2], 0x4E = xor2 [2,3,0,1]
template<int CTRL>
__device__ __forceinline__ float add_dpp(float a, float b){
  return a + __int_as_float(__builtin_amdgcn_update_dpp(
      0, __float_as_int(b), CTRL, 0xF, 0xF, true));
}

// ---------------- K1: input projection GEMM (fp32 VALU) ----------------
__global__ __launch_bounds__(256) void k_inproj(
    const float* __restrict__ x, const float* __restrict__ W,
    const float* __restrict__ bih, const float* __restrict__ bhh,
    float* __restrict__ pre)
{
    __shared__ float xs[64][128];
    const int tid = threadIdx.x;
    const long row0 = (long)blockIdx.x * 64;

    const float4* __restrict__ xv = (const float4*)(x + row0 * 128);
    float4* xsv = (float4*)(&xs[0][0]);
#pragma unroll
    for (int i = 0; i < 8; ++i) xsv[tid + 256 * i] = xv[tid + 256 * i];
    __syncthreads();

    const int tx = tid & 63;
    const int ty = tid >> 6;

    float acc[16][4];
#pragma unroll
    for (int i = 0; i < 16; ++i)
#pragma unroll
        for (int j = 0; j < 4; ++j) acc[i][j] = 0.0f;

#pragma unroll 1
    for (int kc = 0; kc < 16; ++kc) {
        const int k0 = kc * 8;
        float4 w0[4], w1[4];
#pragma unroll
        for (int j = 0; j < 4; ++j) {
            const float* wr = W + (tx + 64 * j) * 128 + k0;
            w0[j] = *(const float4*)wr;
            w1[j] = *(const float4*)(wr + 4);
        }
#pragma unroll
        for (int i = 0; i < 16; ++i) {
            const int r = ty * 16 + i;
            float4 a0 = *(const float4*)(&xs[r][k0]);
            float4 a1 = *(const float4*)(&xs[r][k0 + 4]);
#pragma unroll
            for (int j = 0; j < 4; ++j) {
                float s = acc[i][j];
                s = fmaf(a0.x, w0[j].x, s); s = fmaf(a0.y, w0[j].y, s);
                s = fmaf(a0.z, w0[j].z, s); s = fmaf(a0.w, w0[j].w, s);
                s = fmaf(a1.x, w1[j].x, s); s = fmaf(a1.y, w1[j].y, s);
                s = fmaf(a1.z, w1[j].z, s); s = fmaf(a1.w, w1[j].w, s);
                acc[i][j] = s;
            }
        }
    }

    float bsum[4];
#pragma unroll
    for (int j = 0; j < 4; ++j) { const int g = tx + 64 * j; bsum[j] = bih[g] + bhh[g]; }
#pragma unroll
    for (int i = 0; i < 16; ++i) {
        const long r = row0 + ty * 16 + i;
        float* pr = pre + r * 256;
#pragma unroll
        for (int j = 0; j < 4; ++j) pr[tx + 64 * j] = acc[i][j] + bsum[j];
    }
}

// ---------------- K2: fused 2-layer recurrence + head ----------------
__global__ __attribute__((amdgpu_flat_work_group_size(768, 768)))
void k_fused(
    const float* __restrict__ Whh0, const float* __restrict__ Wih1,
    const float* __restrict__ Whh1,
    const float* __restrict__ bih1, const float* __restrict__ bhh1,
    const float* __restrict__ Wfc,  const float* __restrict__ bfc,
    const float* __restrict__ pre,  float* __restrict__ out)
{
    const int tid = threadIdx.x;
    const int ll  = tid & 3;          // lane-in-quad = k-slice index
    const int q   = tid >> 2;         // quad 0..191: rows 4q..4q+3 (global 0..767)
    const int m   = q >> 6;           // matrix: 0=Whh0, 1=Wih1, 2=Whh1
    const int lay = (m == 2) ? 1 : 0; // h layer my matrix consumes
    const int cA  = (ll >> 1) & 1;    // surviving batch slot
    const int cB  = cA ^ 1;

    __shared__ __align__(16) uint4 wl4[8][768];     // 96KB per-thread weight streams
    __shared__ unsigned hp[2][2][2][32];            // 1KB [par][batch][layer][32u]=64 fp16
    __shared__ float zl[2][768];                    // 6KB dot results [batch][row]

    // ---- one-time: pack my 4 rows (permuted) x k-slice into my stream ----
    {
        const float* Wm = (m == 0) ? Whh0 : ((m == 1) ? Wih1 : Whh1);
        const int rofs[4] = { (ll & 1), 2 + (ll & 1), 1 - (ll & 1), 3 - (ll & 1) };
#pragma unroll
        for (int rs = 0; rs < 4; ++rs) {
            const int rr = (4 * q + rofs[rs]) & 255;       // row within matrix
            const float4* src = (const float4*)(Wm + rr * 64 + 16 * ll);
            float4 f0 = src[0], f1 = src[1], f2 = src[2], f3 = src[3];
            uint4 u0, u1;
            u0.x = packh(f0.x, f0.y); u0.y = packh(f0.z, f0.w);
            u0.z = packh(f1.x, f1.y); u0.w = packh(f1.z, f1.w);
            u1.x = packh(f2.x, f2.y); u1.y = packh(f2.z, f2.w);
            u1.z = packh(f3.x, f3.y); u1.w = packh(f3.z, f3.w);
            wl4[rs * 2 + 0][tid] = u0;
            wl4[rs * 2 + 1][tid] = u1;
        }
    }
    if (tid < 256) ((unsigned*)hp)[tid] = 0;   // h_{-1}=0 both parities

    // ---- updater role (tid<256): c=batch, l=layer, j=unit ----
    const int c_u = tid >> 7;
    const int l_u = (tid >> 6) & 1;
    const int j_u = tid & 63;
    const long bb = (long)blockIdx.x * 2;
    float bias1v[4] = {0, 0, 0, 0};
    float pc[4] = {0, 0, 0, 0};
    if (tid < 256) {
        if (l_u == 1) {
#pragma unroll
            for (int g = 0; g < 4; ++g) bias1v[g] = bih1[g * 64 + j_u] + bhh1[g * 64 + j_u];
        } else {
            const float* pb = pre + (bb + c_u) * TSTEPS * 256;
#pragma unroll
            for (int g = 0; g < 4; ++g) pc[g] = pb[g * 64 + j_u];   // t=0
        }
    }
    float cst = 0.0f, h1last = 0.0f;
    int p = 0;
    __syncthreads();

#pragma unroll 1
    for (int n = 0; n <= TSTEPS; ++n) {
        // prefetch pre for t=n+1 (layer-0 updaters)
        float pn[4] = {0, 0, 0, 0};
        if (tid < 256 && l_u == 0) {
            const int tn = (n + 1 < TSTEPS) ? n + 1 : 0;
            const float* pb = pre + ((bb + c_u) * TSTEPS + tn) * 256;
#pragma unroll
            for (int g = 0; g < 4; ++g) pn[g] = pb[g * 64 + j_u];
        }

        // ---- h slices (my k-slice, both batch slots): 4 b128, broadcast ----
        uint4 hA0 = *(const uint4*)&hp[p][cA][lay][ll * 8];
        uint4 hA1 = *(const uint4*)&hp[p][cA][lay][ll * 8 + 4];
        uint4 hB0 = *(const uint4*)&hp[p][cB][lay][ll * 8];
        uint4 hB1 = *(const uint4*)&hp[p][cB][lay][ll * 8 + 4];

        // ---- partial dots: 4 row-slots x 2 batch-slots, k=16 each ----
        float pA[4], pB[4];
#pragma unroll
        for (int rs = 0; rs < 4; ++rs) {
            uint4 w0 = wl4[rs * 2 + 0][tid];
            uint4 w1 = wl4[rs * 2 + 1][tid];
            float a = 0.0f, bA = 0.0f;
            a  = dot2f(w0.x, hA0.x, a);  a  = dot2f(w0.y, hA0.y, a);
            a  = dot2f(w0.z, hA0.z, a);  a  = dot2f(w0.w, hA0.w, a);
            a  = dot2f(w1.x, hA1.x, a);  a  = dot2f(w1.y, hA1.y, a);
            a  = dot2f(w1.z, hA1.z, a);  a  = dot2f(w1.w, hA1.w, a);
            bA = dot2f(w0.x, hB0.x, bA); bA = dot2f(w0.y, hB0.y, bA);
            bA = dot2f(w0.z, hB0.z, bA); bA = dot2f(w0.w, hB0.w, bA);
            bA = dot2f(w1.x, hB1.x, bA); bA = dot2f(w1.y, hB1.y, bA);
            bA = dot2f(w1.z, hB1.z, bA); bA = dot2f(w1.w, hB1.w, bA);
            pA[rs] = a; pB[rs] = bA;
        }

        // ---- select-free merges ----
        // stage 1 (xor1): row merge — my slot rs pairs with neighbor's rs+2
        float q0A = add_dpp<0xB1>(pA[0], pA[2]);
        float q1A = add_dpp<0xB1>(pA[1], pA[3]);
        float q0B = add_dpp<0xB1>(pB[0], pB[2]);
        float q1B = add_dpp<0xB1>(pB[1], pB[3]);
        // stage 2 (xor2): batch merge — my A pairs with neighbor's B
        float r0 = add_dpp<0x4E>(q0A, q0B);
        float r1 = add_dpp<0x4E>(q1A, q1B);

        const int R0 = 4 * q + (ll & 1);
        zl[cA][R0]     = r0;
        zl[cA][R0 + 2] = r1;
        __syncthreads();   // zl ready

        // ---- cell updates ----
        if (tid < 256) {
            const bool valid = (l_u == 0) ? (n < TSTEPS) : (n >= 1);
            if (valid) {
                float z[4];
                if (l_u == 0) {
#pragma unroll
                    for (int g = 0; g < 4; ++g) z[g] = pc[g] + zl[c_u][g * 64 + j_u];
                } else {
#pragma unroll
                    for (int g = 0; g < 4; ++g)
                        z[g] = bias1v[g] + zl[c_u][256 + g * 64 + j_u] + zl[c_u][512 + g * 64 + j_u];
                }
                float i_ = sigf(z[0]), f_ = sigf(z[1]), g_ = tanh_fast(z[2]), o_ = sigf(z[3]);
                cst = fmaf(f_, cst, i_ * g_);
                float h = o_ * tanh_fast(cst);
                if (l_u) h1last = h;
                ((unsigned short*)&hp[p ^ 1][c_u][l_u][0])[j_u] =
                    __builtin_bit_cast(unsigned short, (_Float16)h);
            }
        }
        __syncthreads();   // new h visible
        p ^= 1;
        if (tid < 256 && l_u == 0) {
            pc[0] = pn[0]; pc[1] = pn[1]; pc[2] = pn[2]; pc[3] = pn[3];
        }
    }

    // ---- head: out[bb+c] = h1_{T-1} . Wfc + bfc ----
    if (tid < 256 && l_u == 1) {
        float v = h1last * Wfc[j_u];
#pragma unroll
        for (int off = 32; off > 0; off >>= 1) v += __shfl_down(v, off);
        if (j_u == 0) out[bb + c_u] = v + bfc[0];
    }
}

extern "C" void kernel_launch(void* const* d_in, const int* in_sizes, int n_in,
                              void* d_out, int out_size, void* d_ws, size_t ws_size,
                              hipStream_t stream)
{
    const float* x    = (const float*)d_in[0];
    const float* Wih0 = (const float*)d_in[1];
    const float* Whh0 = (const float*)d_in[2];
    const float* bih0 = (const float*)d_in[3];
    const float* bhh0 = (const float*)d_in[4];
    const float* Wih1 = (const float*)d_in[5];
    const float* Whh1 = (const float*)d_in[6];
    const float* bih1 = (const float*)d_in[7];
    const float* bhh1 = (const float*)d_in[8];
    const float* Wfc  = (const float*)d_in[9];
    const float* bfc  = (const float*)d_in[10];
    float* out = (float*)d_out;
    float* pre = (float*)d_ws;  // [B][T][256] fp32 = 256 MiB

    k_inproj<<<4096, 256, 0, stream>>>(x, Wih0, bih0, bhh0, pre);
    k_fused<<<256, 768, 0, stream>>>(Whh0, Wih1, Whh1, bih1, bhh1, Wfc, bfc, pre, out);
}

// Round 15
// 642.312 us; speedup vs baseline: 2.0422x; 1.3120x over previous
//
#include <hip/hip_runtime.h>

// LSTM B=512,T=512,D=128,H=64,O=1. Gate order i,f,g,o.
// K1: pre = x@Wih0^T + bih0+bhh0 — NOW MFMA fp16 (was fp32 VALU, 270us @ 40%
//   of vector peak while matrix cores idled). mfma_f32_16x16x32_f16, fragment
//   layouts = R5's end-to-end-verified bf16 ones (A: lane=(m=l&15, kgrp=l>>4);
//   B: lane=(n=l&15, kgrp); C: row=(l>>4)*4+reg, col=l&15).
//   Block: 64 M-rows x 256 N, K=128 one-shot in LDS (fp16, +8 pad -> 2-way max
//   on frag reads). x read ONCE from HBM (no N-split). Wave w owns N=w*64..+64,
//   all 4 M-tiles -> B-frags reused 4x; 32 b128 + 64 MFMA per wave.
//   Error: fp16 one-shot GEMM adds ~6e-4 pre-error -> ~1e-3 end-to-end combined
//   with K2's 4.9e-4; threshold 3.7e-3. Fallback if exceeded: bf16x3.
// K2: UNCHANGED from R13 (547us, absmax 4.9e-4, LDS-stationary fp16 weights,
//   DS-minimized b128 streams + select-free DPP merge). One change per round.
// ws: 512*512*256*4 = 256 MiB fp32 pre (written by K1, read-only in K2).

#define TSTEPS 512

typedef _Float16 h2v __attribute__((ext_vector_type(2)));
typedef _Float16 half8 __attribute__((ext_vector_type(8)));
typedef __attribute__((ext_vector_type(4))) float facc;
union HU { unsigned u; h2v h; };

__device__ __forceinline__ float sigf(float x){ return 1.0f/(1.0f+__expf(-x)); }
__device__ __forceinline__ float tanh_fast(float x){
  float ax=fabsf(x); float e=__expf(-2.0f*ax); float r=(1.0f-e)/(1.0f+e); return copysignf(r,x);
}
__device__ __forceinline__ unsigned packh(float a, float b){
  unsigned short la = __builtin_bit_cast(unsigned short, (_Float16)a);
  unsigned short lb = __builtin_bit_cast(unsigned short, (_Float16)b);
  return (unsigned)la | ((unsigned)lb << 16);
}
__device__ __forceinline__ float dot2f(unsigned wu, unsigned hu, float acc){
#if __has_builtin(__builtin_amdgcn_fdot2)
  HU w; w.u = wu; HU x; x.u = hu;
  return __builtin_amdgcn_fdot2(w.h, x.h, acc, false);
#else
  HU w; w.u = wu; HU x; x.u = hu;
  acc = fmaf((float)w.h[0], (float)x.h[0], acc);
  acc = fmaf((float)w.h[1], (float)x.h[1], acc);
  return acc;
#endif
}
// a + dpp_quad_perm(b); 0xB1 = xor1 [1,0,3,2], 0x4E = xor2 [2,3,0,1]
template<int CTRL>
__device__ __forceinline__ float add_dpp(float a, float b){
  return a + __int_as_float(__builtin_amdgcn_update_dpp(
      0, __float_as_int(b), CTRL, 0xF, 0xF, true));
}

// ---------------- K1: input projection GEMM (fp16 MFMA) ----------------
// grid 4096 x 256 thr. Tile M=64 x N=256, K=128 one-shot.
__global__ __launch_bounds__(256) void k_inproj(
    const float* __restrict__ x, const float* __restrict__ W,
    const float* __restrict__ bih, const float* __restrict__ bhh,
    float* __restrict__ pre)
{
    __shared__ __align__(16) _Float16 Ah[64][136];    // 17.4 KB (x tile)
    __shared__ __align__(16) _Float16 Bh[256][136];   // 69.6 KB (W, all gates)
    const int tid = threadIdx.x;
    const long row0 = (long)blockIdx.x * 64;

    // ---- stage A: 64 rows x 128 k of x -> fp16 ----
    {
        const int r = tid >> 2, c0 = (tid & 3) * 32;
        const float4* src = (const float4*)(x + (row0 + r) * 128 + c0);
#pragma unroll
        for (int i = 0; i < 4; ++i) {
            float4 v0 = src[2 * i], v1 = src[2 * i + 1];
            half8 hv = { (_Float16)v0.x, (_Float16)v0.y, (_Float16)v0.z, (_Float16)v0.w,
                         (_Float16)v1.x, (_Float16)v1.y, (_Float16)v1.z, (_Float16)v1.w };
            *(half8*)&Ah[r][c0 + 8 * i] = hv;
        }
    }
    // ---- stage B: W row n = tid (256 rows x 128 k) -> fp16 ----
    {
        const float4* src = (const float4*)(W + tid * 128);
#pragma unroll
        for (int i = 0; i < 16; ++i) {
            float4 v0 = src[2 * i], v1 = src[2 * i + 1];
            half8 hv = { (_Float16)v0.x, (_Float16)v0.y, (_Float16)v0.z, (_Float16)v0.w,
                         (_Float16)v1.x, (_Float16)v1.y, (_Float16)v1.z, (_Float16)v1.w };
            *(half8*)&Bh[tid][8 * i] = hv;
        }
    }
    __syncthreads();

    const int w  = tid >> 6;
    const int l  = tid & 63;
    const int lm = l & 15;
    const int lk = l >> 4;
    const int n0 = w * 64;

    facc acc[4][4];
#pragma unroll
    for (int mi = 0; mi < 4; ++mi)
#pragma unroll
        for (int ni = 0; ni < 4; ++ni) acc[mi][ni] = (facc){0.f, 0.f, 0.f, 0.f};

#pragma unroll
    for (int ks = 0; ks < 4; ++ks) {
        const int kk = ks * 32 + lk * 8;
        half8 Af[4], Bf[4];
#pragma unroll
        for (int mi = 0; mi < 4; ++mi) Af[mi] = *(const half8*)&Ah[mi * 16 + lm][kk];
#pragma unroll
        for (int ni = 0; ni < 4; ++ni) Bf[ni] = *(const half8*)&Bh[n0 + ni * 16 + lm][kk];
#pragma unroll
        for (int mi = 0; mi < 4; ++mi)
#pragma unroll
            for (int ni = 0; ni < 4; ++ni)
                acc[mi][ni] = __builtin_amdgcn_mfma_f32_16x16x32_f16(
                    Af[mi], Bf[ni], acc[mi][ni], 0, 0, 0);
    }

    // ---- epilogue: +bias, store fp32 ----
    float bs[4];
#pragma unroll
    for (int ni = 0; ni < 4; ++ni) {
        const int n = n0 + ni * 16 + lm;
        bs[ni] = bih[n] + bhh[n];
    }
#pragma unroll
    for (int mi = 0; mi < 4; ++mi) {
#pragma unroll
        for (int ni = 0; ni < 4; ++ni) {
            const int n = n0 + ni * 16 + lm;
#pragma unroll
            for (int r = 0; r < 4; ++r) {
                const long row = row0 + mi * 16 + lk * 4 + r;
                pre[row * 256 + n] = acc[mi][ni][r] + bs[ni];
            }
        }
    }
}

// ---------------- K2: fused 2-layer recurrence + head (R13, unchanged) ------
__global__ __attribute__((amdgpu_flat_work_group_size(768, 768)))
void k_fused(
    const float* __restrict__ Whh0, const float* __restrict__ Wih1,
    const float* __restrict__ Whh1,
    const float* __restrict__ bih1, const float* __restrict__ bhh1,
    const float* __restrict__ Wfc,  const float* __restrict__ bfc,
    const float* __restrict__ pre,  float* __restrict__ out)
{
    const int tid = threadIdx.x;
    const int ll  = tid & 3;          // lane-in-quad = k-slice index
    const int q   = tid >> 2;         // quad 0..191: rows 4q..4q+3 (global 0..767)
    const int m   = q >> 6;           // matrix: 0=Whh0, 1=Wih1, 2=Whh1
    const int lay = (m == 2) ? 1 : 0; // h layer my matrix consumes
    const int cA  = (ll >> 1) & 1;    // surviving batch slot
    const int cB  = cA ^ 1;

    __shared__ __align__(16) uint4 wl4[8][768];     // 96KB per-thread weight streams
    __shared__ unsigned hp[2][2][2][32];            // 1KB [par][batch][layer][32u]=64 fp16
    __shared__ float zl[2][768];                    // 6KB dot results [batch][row]

    // ---- one-time: pack my 4 rows (permuted) x k-slice into my stream ----
    {
        const float* Wm = (m == 0) ? Whh0 : ((m == 1) ? Wih1 : Whh1);
        const int rofs[4] = { (ll & 1), 2 + (ll & 1), 1 - (ll & 1), 3 - (ll & 1) };
#pragma unroll
        for (int rs = 0; rs < 4; ++rs) {
            const int rr = (4 * q + rofs[rs]) & 255;       // row within matrix
            const float4* src = (const float4*)(Wm + rr * 64 + 16 * ll);
            float4 f0 = src[0], f1 = src[1], f2 = src[2], f3 = src[3];
            uint4 u0, u1;
            u0.x = packh(f0.x, f0.y); u0.y = packh(f0.z, f0.w);
            u0.z = packh(f1.x, f1.y); u0.w = packh(f1.z, f1.w);
            u1.x = packh(f2.x, f2.y); u1.y = packh(f2.z, f2.w);
            u1.z = packh(f3.x, f3.y); u1.w = packh(f3.z, f3.w);
            wl4[rs * 2 + 0][tid] = u0;
            wl4[rs * 2 + 1][tid] = u1;
        }
    }
    if (tid < 256) ((unsigned*)hp)[tid] = 0;   // h_{-1}=0 both parities

    // ---- updater role (tid<256): c=batch, l=layer, j=unit ----
    const int c_u = tid >> 7;
    const int l_u = (tid >> 6) & 1;
    const int j_u = tid & 63;
    const long bb = (long)blockIdx.x * 2;
    float bias1v[4] = {0, 0, 0, 0};
    float pc[4] = {0, 0, 0, 0};
    if (tid < 256) {
        if (l_u == 1) {
#pragma unroll
            for (int g = 0; g < 4; ++g) bias1v[g] = bih1[g * 64 + j_u] + bhh1[g * 64 + j_u];
        } else {
            const float* pb = pre + (bb + c_u) * TSTEPS * 256;
#pragma unroll
            for (int g = 0; g < 4; ++g) pc[g] = pb[g * 64 + j_u];   // t=0
        }
    }
    float cst = 0.0f, h1last = 0.0f;
    int p = 0;
    __syncthreads();

#pragma unroll 1
    for (int n = 0; n <= TSTEPS; ++n) {
        // prefetch pre for t=n+1 (layer-0 updaters)
        float pn[4] = {0, 0, 0, 0};
        if (tid < 256 && l_u == 0) {
            const int tn = (n + 1 < TSTEPS) ? n + 1 : 0;
            const float* pb = pre + ((bb + c_u) * TSTEPS + tn) * 256;
#pragma unroll
            for (int g = 0; g < 4; ++g) pn[g] = pb[g * 64 + j_u];
        }

        // ---- h slices (my k-slice, both batch slots): 4 b128, broadcast ----
        uint4 hA0 = *(const uint4*)&hp[p][cA][lay][ll * 8];
        uint4 hA1 = *(const uint4*)&hp[p][cA][lay][ll * 8 + 4];
        uint4 hB0 = *(const uint4*)&hp[p][cB][lay][ll * 8];
        uint4 hB1 = *(const uint4*)&hp[p][cB][lay][ll * 8 + 4];

        // ---- partial dots: 4 row-slots x 2 batch-slots, k=16 each ----
        float pA[4], pB[4];
#pragma unroll
        for (int rs = 0; rs < 4; ++rs) {
            uint4 w0 = wl4[rs * 2 + 0][tid];
            uint4 w1 = wl4[rs * 2 + 1][tid];
            float a = 0.0f, bA = 0.0f;
            a  = dot2f(w0.x, hA0.x, a);  a  = dot2f(w0.y, hA0.y, a);
            a  = dot2f(w0.z, hA0.z, a);  a  = dot2f(w0.w, hA0.w, a);
            a  = dot2f(w1.x, hA1.x, a);  a  = dot2f(w1.y, hA1.y, a);
            a  = dot2f(w1.z, hA1.z, a);  a  = dot2f(w1.w, hA1.w, a);
            bA = dot2f(w0.x, hB0.x, bA); bA = dot2f(w0.y, hB0.y, bA);
            bA = dot2f(w0.z, hB0.z, bA); bA = dot2f(w0.w, hB0.w, bA);
            bA = dot2f(w1.x, hB1.x, bA); bA = dot2f(w1.y, hB1.y, bA);
            bA = dot2f(w1.z, hB1.z, bA); bA = dot2f(w1.w, hB1.w, bA);
            pA[rs] = a; pB[rs] = bA;
        }

        // ---- select-free merges ----
        float q0A = add_dpp<0xB1>(pA[0], pA[2]);
        float q1A = add_dpp<0xB1>(pA[1], pA[3]);
        float q0B = add_dpp<0xB1>(pB[0], pB[2]);
        float q1B = add_dpp<0xB1>(pB[1], pB[3]);
        float r0 = add_dpp<0x4E>(q0A, q0B);
        float r1 = add_dpp<0x4E>(q1A, q1B);

        const int R0 = 4 * q + (ll & 1);
        zl[cA][R0]     = r0;
        zl[cA][R0 + 2] = r1;
        __syncthreads();   // zl ready

        // ---- cell updates ----
        if (tid < 256) {
            const bool valid = (l_u == 0) ? (n < TSTEPS) : (n >= 1);
            if (valid) {
                float z[4];
                if (l_u == 0) {
#pragma unroll
                    for (int g = 0; g < 4; ++g) z[g] = pc[g] + zl[c_u][g * 64 + j_u];
                } else {
#pragma unroll
                    for (int g = 0; g < 4; ++g)
                        z[g] = bias1v[g] + zl[c_u][256 + g * 64 + j_u] + zl[c_u][512 + g * 64 + j_u];
                }
                float i_ = sigf(z[0]), f_ = sigf(z[1]), g_ = tanh_fast(z[2]), o_ = sigf(z[3]);
                cst = fmaf(f_, cst, i_ * g_);
                float h = o_ * tanh_fast(cst);
                if (l_u) h1last = h;
                ((unsigned short*)&hp[p ^ 1][c_u][l_u][0])[j_u] =
                    __builtin_bit_cast(unsigned short, (_Float16)h);
            }
        }
        __syncthreads();   // new h visible
        p ^= 1;
        if (tid < 256 && l_u == 0) {
            pc[0] = pn[0]; pc[1] = pn[1]; pc[2] = pn[2]; pc[3] = pn[3];
        }
    }

    // ---- head: out[bb+c] = h1_{T-1} . Wfc + bfc ----
    if (tid < 256 && l_u == 1) {
        float v = h1last * Wfc[j_u];
#pragma unroll
        for (int off = 32; off > 0; off >>= 1) v += __shfl_down(v, off);
        if (j_u == 0) out[bb + c_u] = v + bfc[0];
    }
}

extern "C" void kernel_launch(void* const* d_in, const int* in_sizes, int n_in,
                              void* d_out, int out_size, void* d_ws, size_t ws_size,
                              hipStream_t stream)
{
    const float* x    = (const float*)d_in[0];
    const float* Wih0 = (const float*)d_in[1];
    const float* Whh0 = (const float*)d_in[2];
    const float* bih0 = (const float*)d_in[3];
    const float* bhh0 = (const float*)d_in[4];
    const float* Wih1 = (const float*)d_in[5];
    const float* Whh1 = (const float*)d_in[6];
    const float* bih1 = (const float*)d_in[7];
    const float* bhh1 = (const float*)d_in[8];
    const float* Wfc  = (const float*)d_in[9];
    const float* bfc  = (const float*)d_in[10];
    float* out = (float*)d_out;
    float* pre = (float*)d_ws;  // [B][T][256] fp32 = 256 MiB

    k_inproj<<<4096, 256, 0, stream>>>(x, Wih0, bih0, bhh0, pre);
    k_fused<<<256, 768, 0, stream>>>(Whh0, Wih1, Whh1, bih1, bhh1, Wfc, bfc, pre, out);
}